// Round 3
// baseline (721.912 us; speedup 1.0000x reference)
//
#include <hip/hip_runtime.h>
#include <hip/hip_bf16.h>
#include <math.h>

#define B_  32
#define T_  2048
#define H_  1024
#define LD_ 1024
#define M_  (B_*T_)   // 65536 rows of enc

typedef __attribute__((ext_vector_type(8))) short bf16x8;
typedef __attribute__((ext_vector_type(4))) float f32x4;

// W2 [H, LD] fp32 -> w2p bf16 k-grouped: w2p[(k/8)*LD*8 + n*8 + (k%8)]
__global__ void convert_w2(const float* __restrict__ W2, __hip_bfloat16* __restrict__ w2p) {
  int idx = blockIdx.x * 256 + threadIdx.x;        // 128K threads
  int kg = idx >> 10, n = idx & 1023;
  __align__(16) __hip_bfloat16 h[8];
#pragma unroll
  for (int j = 0; j < 8; ++j)
    h[j] = __float2bfloat16(W2[(size_t)(kg * 8 + j) * LD_ + n]);
  *reinterpret_cast<uint4*>(&w2p[(size_t)kg * (LD_ * 8) + n * 8]) =
      *reinterpret_cast<const uint4*>(h);
}

// enc [M,H] fp32 -> encp bf16 packed fragment layout:
//   encp[ (rb*128 + kg)*128 + rlow*8 + e ]  where r = rb*16+rlow, k = kg*8+e.
// Per 16-row block: coalesced float4 reads -> LDS reorder -> one 32KB contiguous write.
__global__ __launch_bounds__(256)
void convert_enc(const float* __restrict__ enc, __hip_bfloat16* __restrict__ encp) {
  __shared__ __hip_bfloat16 sb[16][H_ + 8];   // row stride 2064B: 16-lane read = 2-way (free)
  const int rb = blockIdx.x;                  // 4096 row-blocks
  const int tid = threadIdx.x;
  const float4* src = reinterpret_cast<const float4*>(enc + (size_t)rb * 16 * H_);
#pragma unroll
  for (int p = 0; p < 16; ++p) {
    int idx = p * 256 + tid;                  // float4 index within 16x256
    int r = idx >> 8, c4 = idx & 255;
    float4 f = src[idx];
    __align__(8) __hip_bfloat16 h[4];
    h[0] = __float2bfloat16(f.x); h[1] = __float2bfloat16(f.y);
    h[2] = __float2bfloat16(f.z); h[3] = __float2bfloat16(f.w);
    *reinterpret_cast<uint2*>(&sb[r][c4 * 4]) = *reinterpret_cast<const uint2*>(h);
  }
  __syncthreads();
  // write 32KB contiguous: chunk c (16B): c = kg*16 + rlow -> sb[rlow][kg*8..+8]
  uint4* dst = reinterpret_cast<uint4*>((char*)encp + (size_t)rb * 32768);
#pragma unroll
  for (int p = 0; p < 8; ++p) {
    int c = p * 256 + tid;
    int kg = c >> 4, rlow = c & 15;
    dst[c] = *reinterpret_cast<const uint4*>(&sb[rlow][kg * 8]);
  }
}

// dec_w[b][l] = sum_h dec[b][h] * W1[h][l] + b1[l]
__global__ void dec_proj(const float* __restrict__ dec, const float* __restrict__ W1,
                         const float* __restrict__ b1, float* __restrict__ dec_w) {
  __shared__ float sdec[H_];
  int bb = blockIdx.x >> 2;
  int l = (blockIdx.x & 3) * 256 + threadIdx.x;
  for (int i = threadIdx.x; i < H_; i += 256) sdec[i] = dec[bb * H_ + i];
  __syncthreads();
  float a0 = 0.f, a1 = 0.f, a2 = 0.f, a3 = 0.f;
  for (int h = 0; h < H_; h += 4) {
    a0 += sdec[h + 0] * W1[(h + 0) * LD_ + l];
    a1 += sdec[h + 1] * W1[(h + 1) * LD_ + l];
    a2 += sdec[h + 2] * W1[(h + 2) * LD_ + l];
    a3 += sdec[h + 3] * W1[(h + 3) * LD_ + l];
  }
  dec_w[bb * LD_ + l] = (a0 + a1) + (a2 + a3) + b1[l];
}

// Fused: enc_w tile via bf16 MFMA, then score[m] += sum_n tanh(dec_w[b,n]*(enc_w+b2[n]))*V[n]
// v4: ZERO LDS, ZERO barriers. Both MFMA operands are per-lane-contiguous 16B in the
//     packed layouts (encp / w2p) -> direct global->reg loads, register double-buffer
//     depth-2. Waves run fully independently; stalls decorrelate; compiler emits
//     counted vmcnt(12) instead of full drains. 12 dwordx4 loads per 32 MFMAs.
template<bool BF16A>
__global__ __launch_bounds__(256, 2)
void score_gemm(const float* __restrict__ enc,
                const __hip_bfloat16* __restrict__ encp,
                const __hip_bfloat16* __restrict__ w2p,
                const float* __restrict__ dec_w,
                const float* __restrict__ b2,
                const float* __restrict__ V,
                float* __restrict__ score) {
  const int tid  = threadIdx.x;
  const int lane = tid & 63;
  const int wave = tid >> 6;
  const int wm = wave >> 1, wn = wave & 1;       // 2x2 wave grid
  // T1: XCD-aware bijective swizzle (nwg=2048 %8==0): 4 nb-blocks of one mb on same XCD L2
  const int bid = blockIdx.x;
  const int swz = (bid & 7) * 256 + (bid >> 3);
  const int mb = swz >> 2, nb = swz & 3;
  const int row0 = mb * 128, col0 = nb * 256;
  const int q = lane >> 4, c15 = lane & 15;

  f32x4 acc[4][8] = {};

  // A (packed bf16): rowblock rb = mb*8 + wm*4 + i; chunk addr (rb*128 + ks*4 + q)*128 + c15*8
  const __hip_bfloat16* apb = encp + ((size_t)(mb * 8 + wm * 4) * 128 + q) * 128 + c15 * 8;
  // A (fp32 fallback): row-contiguous 8 floats at [row0+wm*64+i*16+c15][ks*32+q*8]
  const float* afb = enc + (size_t)(row0 + wm * 64 + c15) * H_ + q * 8;
  // B (packed bf16 w2p): chunk addr ((ks*4+q)*LD + n)*8, n = col0+wn*128+j*16+c15
  const __hip_bfloat16* bpb = w2p + ((size_t)q * LD_ + col0 + wn * 128 + c15) * 8;

  bf16x8 a0[4], b0[8], a1[4], b1[8];
  float4 p0[8], p1[8];

  auto LOADB = [&](bf16x8* bf, int ks) {
    const __hip_bfloat16* p = bpb + (size_t)ks * (4 * LD_ * 8);
#pragma unroll
    for (int j = 0; j < 8; ++j)
      bf[j] = *reinterpret_cast<const bf16x8*>(p + j * (16 * 8));
  };
  auto LOADA = [&](bf16x8* af, float4* ap, int ks) {
    if constexpr (BF16A) {
      const __hip_bfloat16* p = apb + (size_t)ks * (4 * 128);
#pragma unroll
      for (int i = 0; i < 4; ++i)
        af[i] = *reinterpret_cast<const bf16x8*>(p + (size_t)i * (128 * 128));
    } else {
#pragma unroll
      for (int i = 0; i < 4; ++i) {
        const float4* s = reinterpret_cast<const float4*>(afb + (size_t)i * 16 * H_ + ks * 32);
        ap[i * 2]     = s[0];
        ap[i * 2 + 1] = s[1];
      }
    }
  };
  auto CVTA = [&](bf16x8* af, const float4* ap) {
    if constexpr (!BF16A) {
#pragma unroll
      for (int i = 0; i < 4; ++i) {
        __align__(16) __hip_bfloat16 h[8];
        h[0] = __float2bfloat16(ap[i*2].x);   h[1] = __float2bfloat16(ap[i*2].y);
        h[2] = __float2bfloat16(ap[i*2].z);   h[3] = __float2bfloat16(ap[i*2].w);
        h[4] = __float2bfloat16(ap[i*2+1].x); h[5] = __float2bfloat16(ap[i*2+1].y);
        h[6] = __float2bfloat16(ap[i*2+1].z); h[7] = __float2bfloat16(ap[i*2+1].w);
        af[i] = *reinterpret_cast<const bf16x8*>(h);
      }
    }
  };
  auto MFMA = [&](const bf16x8* af, const bf16x8* bf) {
#pragma unroll
    for (int i = 0; i < 4; ++i)
#pragma unroll
      for (int j = 0; j < 8; ++j)
        acc[i][j] = __builtin_amdgcn_mfma_f32_16x16x32_bf16(af[i], bf[j], acc[i][j], 0, 0, 0);
  };

  // 32 k-steps of K=32; static 2-deep register pipeline (named sets, rule #20)
  LOADA(a0, p0, 0); LOADB(b0, 0);
  for (int it = 0; it < 16; ++it) {
    LOADA(a1, p1, 2 * it + 1); LOADB(b1, 2 * it + 1);   // issue next set
    CVTA(a0, p0);
    MFMA(a0, b0);                                       // waits only set0 (vmcnt counted)
    if (it < 15) { LOADA(a0, p0, 2 * it + 2); LOADB(b0, 2 * it + 2); }
    CVTA(a1, p1);
    MFMA(a1, b1);
  }

  // --- fused epilogue: tanh + V-dot + row reduction ---
  const int bb = row0 >> 11;   // batch index (2048 % 128 == 0, no straddle)
  float b2v[8], dwv[8], Vv[8];
#pragma unroll
  for (int j = 0; j < 8; ++j) {
    int n = col0 + wn * 128 + j * 16 + c15;
    b2v[j] = b2[n];
    dwv[j] = dec_w[bb * LD_ + n];
    Vv[j]  = V[n];
  }
#pragma unroll
  for (int i = 0; i < 4; ++i) {
#pragma unroll
    for (int r = 0; r < 4; ++r) {
      float v = 0.f;
#pragma unroll
      for (int j = 0; j < 8; ++j) {
        float e = acc[i][j][r] + b2v[j];          // enc_w + b2  (row=q*4+r, col=c15)
        v += tanhf(dwv[j] * e) * Vv[j];
      }
      v += __shfl_xor(v, 1);
      v += __shfl_xor(v, 2);
      v += __shfl_xor(v, 4);
      v += __shfl_xor(v, 8);                      // sum 16 cols within quad
      if (c15 == 0) {
        int row = row0 + wm * 64 + i * 16 + q * 4 + r;
        atomicAdd(&score[row], v);
      }
    }
  }
}

// softmax over T per batch; bV is softmax-invariant (scalar), omitted
__global__ void softmax_k(const float* __restrict__ score, float* __restrict__ attn) {
  int bb = blockIdx.x;
  int tid = threadIdx.x;
  int lane = tid & 63, wave = tid >> 6;
  __shared__ float red[4];
  float v[8];
  float mx = -3.4e38f;
#pragma unroll
  for (int i = 0; i < 8; ++i) {
    v[i] = score[bb * T_ + i * 256 + tid];
    mx = fmaxf(mx, v[i]);
  }
#pragma unroll
  for (int m = 32; m >= 1; m >>= 1) mx = fmaxf(mx, __shfl_xor(mx, m));
  if (lane == 0) red[wave] = mx;
  __syncthreads();
  mx = fmaxf(fmaxf(red[0], red[1]), fmaxf(red[2], red[3]));
  __syncthreads();
  float s = 0.f;
#pragma unroll
  for (int i = 0; i < 8; ++i) { v[i] = __expf(v[i] - mx); s += v[i]; }
#pragma unroll
  for (int m = 32; m >= 1; m >>= 1) s += __shfl_xor(s, m);
  if (lane == 0) red[wave] = s;
  __syncthreads();
  s = red[0] + red[1] + red[2] + red[3];
  float inv = 1.f / s;
#pragma unroll
  for (int i = 0; i < 8; ++i) attn[bb * T_ + i * 256 + tid] = v[i] * inv;
}

// context[b][h] = sum_t attn[b][t] * enc[b][t][h]
__global__ __launch_bounds__(256)
void context_k(const float* __restrict__ enc, const float* __restrict__ attn,
               float* __restrict__ ctx) {
  const int bb = blockIdx.y;
  const int t0 = blockIdx.x * 128;                 // 16 chunks x 128 t
  __shared__ float sat[128];
  if (threadIdx.x < 128) sat[threadIdx.x] = attn[bb * T_ + t0 + threadIdx.x];
  __syncthreads();
  const float4* base = reinterpret_cast<const float4*>(
      enc + ((size_t)bb * T_ + t0) * H_) + threadIdx.x;   // 256 threads cover full H row
  f32x4 a0 = {}, a1 = {}, a2 = {}, a3 = {};
  for (int t = 0; t < 128; t += 8) {
    float4 v[8];
#pragma unroll
    for (int u = 0; u < 8; ++u) v[u] = base[(size_t)(t + u) * (H_ / 4)];
#pragma unroll
    for (int u = 0; u < 8; ++u) {
      float a = sat[t + u];
      f32x4& d = (u & 2) ? ((u & 1) ? a3 : a2) : ((u & 1) ? a1 : a0);
      d[0] += a * v[u].x; d[1] += a * v[u].y;
      d[2] += a * v[u].z; d[3] += a * v[u].w;
    }
  }
  const int h = threadIdx.x * 4;
  atomicAdd(&ctx[bb * H_ + h + 0], (a0[0] + a1[0]) + (a2[0] + a3[0]));
  atomicAdd(&ctx[bb * H_ + h + 1], (a0[1] + a1[1]) + (a2[1] + a3[1]));
  atomicAdd(&ctx[bb * H_ + h + 2], (a0[2] + a1[2]) + (a2[2] + a3[2]));
  atomicAdd(&ctx[bb * H_ + h + 3], (a0[3] + a1[3]) + (a2[3] + a3[3]));
}

extern "C" void kernel_launch(void* const* d_in, const int* in_sizes, int n_in,
                              void* d_out, int out_size, void* d_ws, size_t ws_size,
                              hipStream_t stream) {
  const float* enc = (const float*)d_in[0];
  const float* dec = (const float*)d_in[1];
  const float* W1  = (const float*)d_in[2];
  const float* b1  = (const float*)d_in[3];
  const float* W2  = (const float*)d_in[4];
  const float* b2  = (const float*)d_in[5];
  const float* V   = (const float*)d_in[6];
  // d_in[7] = bV: softmax-invariant additive scalar -> ignored.

  char* ws = (char*)d_ws;
  __hip_bfloat16* w2p = (__hip_bfloat16*)ws;                       // 2 MB
  float* dec_w = (float*)(ws + (2u << 20));                        // 128 KB
  float* score = (float*)(ws + (2u << 20) + (128u << 10));         // 256 KB
  const size_t encp_off = (2u << 20) + (384u << 10);               // 32KB-aligned
  __hip_bfloat16* encp = (__hip_bfloat16*)(ws + encp_off);         // 128 MB
  const size_t need = encp_off + (size_t)M_ * H_ * 2;
  const bool bf16a = ws_size >= need;

  float* out  = (float*)d_out;
  float* ctx  = out;              // [B, H]   = 32768 floats
  float* attn = out + B_ * H_;    // [B, T, 1] = 65536 floats

  hipMemsetAsync(score, 0, (size_t)M_ * sizeof(float), stream);
  hipMemsetAsync(ctx, 0, (size_t)B_ * H_ * sizeof(float), stream);

  if (bf16a) convert_enc<<<M_ / 16, 256, 0, stream>>>(enc, encp);
  convert_w2<<<(H_ * LD_ / 8) / 256, 256, 0, stream>>>(W2, w2p);
  dec_proj<<<B_ * 4, 256, 0, stream>>>(dec, W1, b1, dec_w);
  if (bf16a)
    score_gemm<true><<<(M_ / 128) * (LD_ / 256), 256, 0, stream>>>(
        enc, encp, w2p, dec_w, b2, V, score);
  else
    score_gemm<false><<<(M_ / 128) * (LD_ / 256), 256, 0, stream>>>(
        enc, encp, w2p, dec_w, b2, V, score);
  softmax_k<<<B_, 256, 0, stream>>>(score, attn);
  context_k<<<dim3(16, B_), 256, 0, stream>>>(enc, attn, ctx);
}